// Round 4
// baseline (120.885 us; speedup 1.0000x reference)
//
#include <hip/hip_runtime.h>
#include <hip/hip_cooperative_groups.h>

namespace cg = cooperative_groups;

#define HW    262144          // 512*512
#define CHW   786432          // 3*HW
#define NBINS 256
#define BPB   4               // blocks per batch (phases 1 & 2)
#define CHUNK (HW / BPB)      // 65536 elements per block

__global__ __launch_bounds__(512, 2) void fused_kernel(
    const float* __restrict__ x,
    const float* __restrict__ W1, const float* __restrict__ b1,
    const float* __restrict__ g1, const float* __restrict__ be1,
    const float* __restrict__ W2, const float* __restrict__ b2,
    const float* __restrict__ g2, const float* __restrict__ be2,
    const float* __restrict__ W3, const float* __restrict__ b3,
    unsigned int* __restrict__ part, float* __restrict__ h1pre,
    float* __restrict__ out)
{
    __shared__ __align__(16) char smem[34816];
    const int tid = threadIdx.x;
    const int g   = blockIdx.x;
    cg::grid_group grid = cg::this_grid();

    // ================= Phase 1: per-batch partial histograms =================
    {
        unsigned int* lh = (unsigned int*)smem;        // 8192 u32 = 32 KB
        const int col = tid & 31;                      // bank-exclusive column
        for (int i = tid; i < NBINS * 32; i += 512) lh[i] = 0u;
        __syncthreads();

        const int b = g >> 2;
        const int p = g & 3;
        const float4* src = (const float4*)(x + (size_t)b * CHW + (size_t)p * CHUNK);

        int i0 = tid;                                  // 32 float4 per thread, 4-deep groups
        for (int grp = 0; grp < 8; ++grp) {
            float4 va = src[i0];
            float4 vb = src[i0 + 512];
            float4 vc = src[i0 + 1024];
            float4 vd = src[i0 + 1536];
            i0 += 2048;
            float vv[16] = {va.x, va.y, va.z, va.w, vb.x, vb.y, vb.z, vb.w,
                            vc.x, vc.y, vc.z, vc.w, vd.x, vd.y, vd.z, vd.w};
#pragma unroll
            for (int j = 0; j < 16; ++j) {
                float f  = vv[j];
                int idx  = (int)floorf(f * 256.0f);
                idx = idx < 0 ? 0 : (idx > 255 ? 255 : idx);
                if (f >= 0.0f && f <= 1.0f) atomicAdd(&lh[idx * 32 + col], 1u);
            }
        }
        __syncthreads();

        if (tid < 256) {
            unsigned int s = 0;
#pragma unroll
            for (int i = 0; i < 32; ++i) s += lh[tid * 32 + ((tid + i) & 31)];
            part[(size_t)g * NBINS + tid] = s;
        }
    }

    grid.sync();

    // ================= Phase 2: reduce partials + layer 1 (pre-BN) =================
    // block g: batch b = g>>2, feature group jg = g&3 (32 features)
    {
        float* row  = (float*)smem;                    // 256 f32
        float* pd2  = (float*)(smem + 1024);           // 32*17 f32
        float* sred = (float*)(smem + 1024 + 2304);    // 4 f32

        const int b  = g >> 2;
        const int jg = g & 3;

        if (tid < 256) {
            const unsigned int* pp = part + (size_t)(b * 4) * NBINS + tid;
            unsigned int s = pp[0] + pp[256] + pp[512] + pp[768];
            row[tid] = (float)s;
        }
        __syncthreads();

        if (tid < 256) {                               // waves 0..3: total count S
            float s = row[tid];
#pragma unroll
            for (int off = 32; off > 0; off >>= 1) s += __shfl_xor(s, off);
            if ((tid & 63) == 0) sred[tid >> 6] = s;
        }
        __syncthreads();
        const float S   = sred[0] + sred[1] + sred[2] + sred[3];
        const float inv = 1.0f / (S + 1e-6f);

        {
            const int jj  = tid & 31;
            const int seg = tid >> 5;                  // 16 segments of 16 cols
            const int j   = jg * 32 + jj;
            const float4* wrow = (const float4*)(W1 + (size_t)j * 256 + seg * 16);
            const float4* rseg = (const float4*)(row + seg * 16);
            float a0 = 0.f, a1 = 0.f, a2 = 0.f, a3 = 0.f;
#pragma unroll
            for (int i = 0; i < 4; ++i) {
                float4 wv = wrow[i];
                float4 rv = rseg[i];
                a0 += wv.x * rv.x; a1 += wv.y * rv.y;
                a2 += wv.z * rv.z; a3 += wv.w * rv.w;
            }
            pd2[jj * 17 + seg] = (a0 + a1) + (a2 + a3);
        }
        __syncthreads();

        if (tid < 32) {
            float s = 0.f;
#pragma unroll
            for (int sg = 0; sg < 16; ++sg) s += pd2[tid * 17 + sg];
            h1pre[b * 128 + jg * 32 + tid] = s * inv + b1[jg * 32 + tid];
        }
    }

    grid.sync();

    // ================= Phase 3: BN1+ReLU -> L2 -> BN2+ReLU -> L3 (block 0) =================
    if (g == 0) {
        float*  pd  = (float*)smem;                    // 2 * 4096 f32 = 32 KB
        float2* ss1 = (float2*)(smem + 32768);         // 128 float2
        float2* ss2 = (float2*)(smem + 32768 + 1024);  // 64 float2

        const int w   = tid >> 6;                      // wave 0..7
        const int b   = tid & 63;                      // batch = lane
        const int h   = w & 1;                         // k-half of layer-1 features
        const int jg3 = w >> 1;                        // output j-group (16 wide)

        // 3a: load this lane's batch row half into registers
        float r[64];
        {
            const float* hp = h1pre + b * 128 + h * 64;
#pragma unroll
            for (int kk = 0; kk < 16; ++kk) {
                float4 v = *(const float4*)(hp + 4 * kk);
                r[4*kk+0] = v.x; r[4*kk+1] = v.y; r[4*kk+2] = v.z; r[4*kk+3] = v.w;
            }
        }

        // 3b: BN1 stats — wave w owns features f in [64h + 16*jg3, +16), disjoint cover
#pragma unroll
        for (int i = 0; i < 16; ++i) {
            const int idx = jg3 * 16 + i;
            float v = r[idx];
            float s = v, q = v * v;
#pragma unroll
            for (int off = 32; off > 0; off >>= 1) {
                s += __shfl_xor(s, off);
                q += __shfl_xor(q, off);
            }
            const float mu  = s * (1.0f / 64.0f);
            const float var = q * (1.0f / 64.0f) - mu * mu;
            const int   f   = h * 64 + idx;
            const float sc  = g1[f] * rsqrtf(var + 1e-5f);
            const float sh  = be1[f] - mu * sc;
            if (b == 0) ss1[f] = make_float2(sc, sh);
        }
        __syncthreads();

        // 3c: normalize + ReLU in registers
#pragma unroll
        for (int k = 0; k < 64; ++k) {
            float2 s2 = ss1[h * 64 + k];
            r[k] = fmaxf(r[k] * s2.x + s2.y, 0.0f);
        }

        // 3d: layer-2 half-dot partials (deterministic 2-way split)
        {
            float* pdh = pd + h * 4096;
            for (int jj = 0; jj < 16; ++jj) {
                const int j = jg3 * 16 + jj;
                const float* w2 = W2 + (size_t)j * 128 + h * 64;
                float a0 = 0.f, a1 = 0.f, a2 = 0.f, a3 = 0.f;
#pragma unroll
                for (int k = 0; k < 64; k += 4) {
                    a0 += r[k+0] * w2[k+0]; a1 += r[k+1] * w2[k+1];
                    a2 += r[k+2] * w2[k+2]; a3 += r[k+3] * w2[k+3];
                }
                pdh[j * 64 + b] = (a0 + a1) + (a2 + a3);
            }
        }
        __syncthreads();

        // 3e: combine halves + bias b2 -> h2 (in pd[0..4095])
        for (int i = tid; i < 4096; i += 512) {
            const int j = i >> 6;
            pd[i] = pd[i] + pd[4096 + i] + b2[j];
        }
        __syncthreads();

        // 3f: BN2 stats — wave w owns j in [8w, 8w+8)
#pragma unroll
        for (int i = 0; i < 8; ++i) {
            const int j = w * 8 + i;
            float v = pd[j * 64 + b];
            float s = v, q = v * v;
#pragma unroll
            for (int off = 32; off > 0; off >>= 1) {
                s += __shfl_xor(s, off);
                q += __shfl_xor(q, off);
            }
            const float mu  = s * (1.0f / 64.0f);
            const float var = q * (1.0f / 64.0f) - mu * mu;
            const float sc  = g2[j] * rsqrtf(var + 1e-5f);
            const float sh  = be2[j] - mu * sc;
            if (b == 0) ss2[j] = make_float2(sc, sh);
        }
        __syncthreads();

        // 3g: normalize + ReLU + layer 3
        if (tid < 64) {
            float acc = b3[0];
#pragma unroll
            for (int j = 0; j < 64; ++j) {
                float2 s2 = ss2[j];
                acc += fmaxf(pd[j * 64 + tid] * s2.x + s2.y, 0.0f) * W3[j];
            }
            out[tid] = acc;
        }
    }
}

extern "C" void kernel_launch(void* const* d_in, const int* in_sizes, int n_in,
                              void* d_out, int out_size, void* d_ws, size_t ws_size,
                              hipStream_t stream) {
    const float* x   = (const float*)d_in[0];
    const float* W1  = (const float*)d_in[1];
    const float* b1  = (const float*)d_in[2];
    const float* g1  = (const float*)d_in[3];
    const float* be1 = (const float*)d_in[4];
    const float* W2  = (const float*)d_in[5];
    const float* b2  = (const float*)d_in[6];
    const float* g2  = (const float*)d_in[7];
    const float* be2 = (const float*)d_in[8];
    const float* W3  = (const float*)d_in[9];
    const float* b3  = (const float*)d_in[10];
    float* out = (float*)d_out;

    unsigned int* part = (unsigned int*)d_ws;                    // 256*256*4 = 256 KB
    float* h1pre       = (float*)((char*)d_ws + (1u << 20));     // 8192 floats

    void* args[] = { (void*)&x, (void*)&W1, (void*)&b1, (void*)&g1, (void*)&be1,
                     (void*)&W2, (void*)&b2, (void*)&g2, (void*)&be2,
                     (void*)&W3, (void*)&b3, (void*)&part, (void*)&h1pre, (void*)&out };
    hipLaunchCooperativeKernel((const void*)fused_kernel, dim3(256), dim3(512),
                               args, 0, stream);
}